// Round 6
// baseline (638.307 us; speedup 1.0000x reference)
//
#include <hip/hip_runtime.h>
#include <math.h>

// FractionalDilationR2: out[b,c,y,x] = max_{dy,dx in [-5,5]} u[b,c,y+dy,x+dx] - k[c,dy+5,dx+5]
// k_c = nu * rho^e * exp(-e * sum_j p[c,j] B_j(theta)),  e = 2a/(2a-1), a = 0.65 (e = 13/3).
//
// Exact pruning: center tap has k=0, so acc >= u[p] >= tileMin. Any tap with
// k >= tileMax - tileMin (valid values only) can never exceed acc -> drop it.
// Per dx column we keep a contiguous [lo,hi] dy-hull of live taps.
//
// R2 (kept): T14 async-STAGE split — 438 -> 397 us.
// R3 (kept): dy-pair + max3 — 397 -> 257 us. Tap math floor: 1.5 VALU/(tap,out).
// R4 (kept): scalar staging, clean min/max path — 257 -> 233.
// R5 (kept): TY=64, 8-wave blocks — 233 -> 212. VALUBusy 97% -> pure issue-bound.
//
// R6 change: static-offset shared-window compute. Counter calibration shows
// ~1930 VALU/wave-tile vs ~1500 tap floor: ~300 is pair-loop control/pointer
// VALU. Fix: (a) one 18-row register window per dx (loads share ONE vaddr,
// all offsets compile-time immediates), (b) fully unrolled dx + fixed pair
// partition (0,1)(2,3)..(10) gated by wave-uniform SALU branches on hull
// overlap (scalar pipe = free), (c) zero addressing VALU in compute. A dead
// tap inside a partially-live pair is harmless (pruned taps never win); fmax
// exact -> output bitwise unchanged.

#define RR 5
#define KS 11
#define NTAPS (KS * KS)     // 121
#define HDIM 512
#define WDIM 512
#define NCH 32
#define TX 64               // output tile width (= lanes in x)
#define TY 64               // output tile height per iteration
#define NWAVES 8            // waves (ty slots) per block
#define VPT 8               // vertical outputs per thread
#define WROWS (KS + VPT - 1) // 18 window rows per dx column
#define TH (TY + 2 * RR)    // 74 tile rows in LDS
#define TW (TX + 2 * RR)    // 74 tile cols
#define PITCH 76            // padded LDS pitch (floats)
#define NJR 10              // staging row-iters: r = tyS + 8*jr < 74
#define NEGF (-1e30f)

// ---- pre-kernel: build the 32x121 kernel table in double, once per launch ----
__global__ void build_ktab_kernel(const float* __restrict__ finsler,
                                  float* __restrict__ ktab) {
    const int c = blockIdx.x;          // 0..31
    const int t = threadIdx.x;         // 0..127
    if (t >= NTAPS) return;
    const int dy = t / KS - RR;
    const int dx = t % KS - RR;
    const double rho = sqrt((double)(dx * dx + dy * dy));
    const double th  = atan2((double)dy, (double)dx);
    const float* pc = finsler + c * 6;
    const double g =
        (double)pc[0] * cos(th)       + (double)pc[1] * sin(th) +
        (double)pc[2] * cos(2.0 * th) + (double)pc[3] * sin(2.0 * th) +
        (double)pc[4] * cos(3.0 * th) + (double)pc[5] * sin(3.0 * th);
    const double e  = 2.0 * 0.65 / (2.0 * 0.65 - 1.0);     // 13/3
    const double nu = (2.0 * 0.65 - 1.0) * pow(2.0 * 0.65, -e);
    const double kvd = (rho == 0.0) ? 0.0 : nu * pow(rho, e) * exp(-e * g);
    ktab[c * NTAPS + t] = (float)kvd;
}

__global__ __launch_bounds__(512, 8) void frac_dilation_kernel(
    const float* __restrict__ u,
    const float* __restrict__ ktab,    // [32,121] precomputed
    float* __restrict__ out)
{
    __shared__ float klds[NTAPS];
    __shared__ float tile[TH * PITCH];
    __shared__ float wmaxs[NWAVES], wmins[NWAVES];
    __shared__ int   lohi_lds[KS];

    const int tx  = threadIdx.x;                                   // 0..63
    // block is 64x8: each wave is exactly one ty row -> ty is wave-uniform.
    const int tyS = __builtin_amdgcn_readfirstlane(threadIdx.y);   // scalar 0..7
    const int tid = tyS * 64 + tx;
    const int p   = blockIdx.y;           // plane index b*32+c
    const int c   = p & (NCH - 1);
    const int ox  = blockIdx.x * TX;

    if (tid < NTAPS) klds[tid] = ktab[c * NTAPS + tid];
    // visible after the first __syncthreads below

    const float* uplane = u   + (size_t)p * (HDIM * WDIM);
    float*       oplane = out + (size_t)p * (HDIM * WDIM);
    const int y0 = tyS * VPT;             // this thread's first output row (scalar)

    // ---- per-lane x geometry, computed once (launch-invariant) ----
    const int  gx0    = ox + tx - RR;            // <= 506, only left edge invalid
    const bool m0     = (gx0 >= 0);
    const bool s1lane = (tx < TW - 64);          // lanes 0..9 handle 2nd strip
    const int  gx1    = ox + tx + 64 - RR;
    const bool m1     = s1lane && (gx1 < WDIM);
    const bool xpad   = (ox == 0) || (ox + TX == WDIM);   // block-uniform

    // staging registers: column cc=tx (all lanes) and cc=tx+64 (lanes tx<10)
    float sreg0[NJR], sreg1[NJR];

    // ---- ISSUE: launch global loads for tile itY into sreg (no waits) ----
    auto issue_tile = [&](int itY) {
        const int oyl = itY * TY;
#pragma unroll
        for (int jr = 0; jr < NJR; ++jr) {
            const int r = tyS + NWAVES * jr;     // scalar
            float v0 = NEGF, v1 = NEGF;
            if (r < TH) {                        // scalar compare
                const int gy = oyl + r - RR;     // scalar
                if (gy >= 0 && gy < HDIM) {      // wave-uniform branch (SALU)
                    const float* row = uplane + (size_t)gy * WDIM;  // s-base
                    if (m0) v0 = row[gx0];       // v-offset load, exec-masked
                    if (m1) v1 = row[gx1];
                }
            }
            sreg0[jr] = v0;
            sreg1[jr] = v1;
        }
    };

    issue_tile(0);   // prologue: loads for first tile in flight

#pragma unroll 1
    for (int itY = 0; itY < HDIM / TY; ++itY) {
        const int oy = itY * TY;

        __syncthreads();   // A: previous compute must finish before tile overwrite

        // ---- WRITE: regs -> LDS, tracking valid-value min/max ----
        float vmax = -3.0e38f, vmin = 3.0e38f;
        const bool clean = !xpad && (itY != 0) && (itY != HDIM / TY - 1);
        if (clean) {
            // no padding anywhere in this tile: select-free tracking
#pragma unroll
            for (int jr = 0; jr < NJR; ++jr) {
                const int r = tyS + NWAVES * jr;
                if (r < TH) {
                    const float v = sreg0[jr];
                    tile[r * PITCH + tx] = v;
                    vmax = fmaxf(vmax, v);
                    vmin = fminf(vmin, v);
                    if (s1lane) {
                        const float w = sreg1[jr];
                        tile[r * PITCH + tx + 64] = w;
                        vmax = fmaxf(vmax, w);
                        vmin = fminf(vmin, w);
                    }
                }
            }
        } else {
#pragma unroll
            for (int jr = 0; jr < NJR; ++jr) {
                const int r = tyS + NWAVES * jr;
                if (r < TH) {
                    {
                        const float v = sreg0[jr];
                        tile[r * PITCH + tx] = v;
                        vmax = fmaxf(vmax, v);                          // NEGF never wins
                        vmin = fminf(vmin, (v < -1e29f) ? 3.0e38f : v); // exclude padding
                    }
                    if (s1lane) {
                        const float w = sreg1[jr];
                        tile[r * PITCH + tx + 64] = w;
                        vmax = fmaxf(vmax, w);
                        vmin = fminf(vmin, (w < -1e29f) ? 3.0e38f : w);
                    }
                }
            }
        }
        // wave-level reduce (width 64)
#pragma unroll
        for (int m = 1; m < 64; m <<= 1) {
            vmax = fmaxf(vmax, __shfl_xor(vmax, m, 64));
            vmin = fminf(vmin, __shfl_xor(vmin, m, 64));
        }
        if (tx == 0) { wmaxs[tyS] = vmax; wmins[tyS] = vmin; }
        __syncthreads();   // B: tile + wave partials visible

        float tmax = wmaxs[0], tmin = wmins[0];
#pragma unroll
        for (int wv = 1; wv < NWAVES; ++wv) {
            tmax = fmaxf(tmax, wmaxs[wv]);
            tmin = fminf(tmin, wmins[wv]);
        }
        const float delta = tmax - tmin;   // >= 0; center tap k=0 always live

        if (tid < KS) {                    // one thread per dx: contiguous dy hull
            int lo = 1, hi = 0;
#pragma unroll
            for (int dy = 0; dy < KS; ++dy) {
                if (klds[dy * KS + tid] <= delta) { if (lo > hi) lo = dy; hi = dy; }
            }
            lohi_lds[tid] = lo | (hi << 16);
        }
        __syncthreads();   // C: hulls visible

        // ---- issue NEXT tile's loads; latency hides under compute below ----
        if (itY + 1 < HDIM / TY) issue_tile(itY + 1);

        // ---- pruned max-plus accumulation, static-offset shared windows ----
        float acc[VPT];
#pragma unroll
        for (int i = 0; i < VPT; ++i) acc[i] = NEGF;

        const float* wcol = &tile[y0 * PITCH + tx];  // single vaddr; all reads
                                                     // below use imm offsets
#pragma unroll
        for (int dx = 0; dx < KS; ++dx) {
            const int lh = __builtin_amdgcn_readfirstlane(lohi_lds[dx]);
            const int lo = lh & 0xffff;
            const int hi = lh >> 16;
            if (lo > hi) continue;           // dead column (uniform branch)

            // 18-row window for this dx, shared by all pairs (static indices)
            float w[WROWS];
#pragma unroll
            for (int r = 0; r < WROWS; ++r)
                w[r] = wcol[r * PITCH + dx];

            // fixed pair partition, overlap-gated (wave-uniform SALU branches)
#pragma unroll
            for (int pp = 0; pp < KS / 2; ++pp) {
                const int dy0 = 2 * pp, dy1 = dy0 + 1;
                if (dy1 >= lo && dy0 <= hi) {
                    const float k0 = klds[dy0 * KS + dx];
                    const float k1 = klds[dy1 * KS + dx];
#pragma unroll
                    for (int i = 0; i < VPT; ++i)
                        acc[i] = fmaxf(acc[i],
                                       fmaxf(w[dy0 + i] - k0,
                                             w[dy1 + i] - k1));
                }
            }
            if (hi == KS - 1) {              // solo top tap dy=10
                const float kT = klds[(KS - 1) * KS + dx];
#pragma unroll
                for (int i = 0; i < VPT; ++i)
                    acc[i] = fmaxf(acc[i], w[KS - 1 + i] - kT);
            }
        }

        // ---- store ----
#pragma unroll
        for (int i = 0; i < VPT; ++i)
            oplane[(oy + y0 + i) * WDIM + ox + tx] = acc[i];
    }
}

extern "C" void kernel_launch(void* const* d_in, const int* in_sizes, int n_in,
                              void* d_out, int out_size, void* d_ws, size_t ws_size,
                              hipStream_t stream) {
    const float* u  = (const float*)d_in[0];   // (8,32,512,512) fp32
    const float* fp = (const float*)d_in[1];   // (32,6) fp32
    float* out  = (float*)d_out;
    float* ktab = (float*)d_ws;                // 32*121 floats = 15.5 KB scratch

    build_ktab_kernel<<<dim3(NCH), dim3(128), 0, stream>>>(fp, ktab);

    dim3 grid(WDIM / TX, 8 * NCH);   // 8 x-strips, 256 planes
    dim3 block(64, NWAVES);
    frac_dilation_kernel<<<grid, block, 0, stream>>>(u, ktab, out);
}